// Round 18
// baseline (79.331 us; speedup 1.0000x reference)
//
#include <hip/hip_runtime.h>
#include <math.h>

#define BB 256
#define VV 4096
#define DD 64
#define NCHUNK 32
#define CHBG 16384   // global chunk bytes: 64 rows x 64 d x 4 B (fp32)
#define CHBL 8192    // LDS chunk bytes:    64 rows x 64 d x 2 B (fp16)

typedef __attribute__((ext_vector_type(8))) _Float16 f16x8;
typedef __attribute__((ext_vector_type(2))) __fp16 fp16x2;   // cvt_pkrtz return type
typedef __attribute__((ext_vector_type(4))) float f32x4;

// ---------------------------------------------------------------------------
// Kernel 1: 512 blocks of 256 thr (4 waves): block = (a, v-half).
// r17 (67.2us, best) + LDS-read-amplification halved: waves = 2 rowgroups x
// 2 colgroups (bf[8][2] = 64 VGPR), so each staged fp16 row is ds_read by 2
// waves, not 4.  256-thr blocks because the toolchain caps 512-thr blocks at
// 128 VGPR (r6/r7/r16 spills); 2 blocks/CU also gives two independent
// barrier domains.  Same schedule as r17: fp16 reg-staging (T14), E/O
// static-named depth-2, counted vmcnt(4), one raw s_barrier per chunk.
// B converted in 2 groups of 4 ct to cap transient VGPRs (r16 confound).
// ---------------------------------------------------------------------------
__global__ __launch_bounds__(256) void topk_sim_kernel(
    const float* __restrict__ F, const float* __restrict__ lan,
    float* __restrict__ max0P, float* __restrict__ max1P)
{
  extern __shared__ __align__(16) char smem[];   // 2 x 8KB fp16 chunk buffers

  const int t = threadIdx.x;
  const int a    = blockIdx.x >> 1;
  const int half = blockIdx.x & 1;
  const int wave = t >> 6;
  const int lane = t & 63;
  const int cl = lane & 15;      // row (A) / col (B/C) within 16x16 tile
  const int o  = lane >> 4;      // k-octet group
  const int rg = wave >> 1;      // row half of each 64-row chunk
  const int cg = wave & 1;       // col half

  const char* gFa = (const char*)(F + (size_t)a * VV * DD
                                  + (size_t)half * 2048 * DD);

  // ---- B fragments: 8 col-tiles x 2 ksubs, fp16; 2 groups of 4 ct ----
  f16x8 bf[8][2];
#pragma unroll
  for (int g = 0; g < 2; ++g) {
    float4 bu4[4][2][2];
#pragma unroll
    for (int ci = 0; ci < 4; ++ci)
#pragma unroll
      for (int s = 0; s < 2; ++s) {
        const float* p = lan + (cg * 128 + (g * 4 + ci) * 16 + cl) * DD
                         + s * 32 + o * 8;
        bu4[ci][s][0] = *(const float4*)p;
        bu4[ci][s][1] = *(const float4*)(p + 4);
      }
#pragma unroll
    for (int ci = 0; ci < 4; ++ci)
#pragma unroll
      for (int s = 0; s < 2; ++s) {
        union { f16x8 v; fp16x2 h[4]; } U;
        U.h[0] = __builtin_amdgcn_cvt_pkrtz(bu4[ci][s][0].x, bu4[ci][s][0].y);
        U.h[1] = __builtin_amdgcn_cvt_pkrtz(bu4[ci][s][0].z, bu4[ci][s][0].w);
        U.h[2] = __builtin_amdgcn_cvt_pkrtz(bu4[ci][s][1].x, bu4[ci][s][1].y);
        U.h[3] = __builtin_amdgcn_cvt_pkrtz(bu4[ci][s][1].z, bu4[ci][s][1].w);
        bf[g * 4 + ci][s] = U.v;
      }
  }

  // ---- staging addressing ----
  // load instr i: 16B at chunk + 4096*i + 16*t -> row = 16i + (t>>4),
  //   d0 = 4*(t&15).  write: fp16 8B at row*128 + swizzled slot.
  const int woff = ((((t & 15) >> 1) ^ ((t >> 4) & 7)) << 4) + (t & 1) * 8;
  const int wrow = (t >> 4) * 128;               // + i*2048 per instr

#define LOADG(S0, S1, S2, S3, CH) {                                   \
    const char* _g = gFa + (size_t)(CH) * CHBG + 16 * t;              \
    S0 = *(const float4*)(_g);                                        \
    S1 = *(const float4*)(_g + 4096);                                 \
    S2 = *(const float4*)(_g + 8192);                                 \
    S3 = *(const float4*)(_g + 12288); }

#define CVTW(S0, S1, S2, S3, BUFP) {                                  \
    char* _b = (BUFP) + wrow + woff;                                  \
    union { uint2 u; fp16x2 h[2]; } _c;                               \
    _c.h[0] = __builtin_amdgcn_cvt_pkrtz(S0.x, S0.y);                 \
    _c.h[1] = __builtin_amdgcn_cvt_pkrtz(S0.z, S0.w);                 \
    *(uint2*)(_b) = _c.u;                                             \
    _c.h[0] = __builtin_amdgcn_cvt_pkrtz(S1.x, S1.y);                 \
    _c.h[1] = __builtin_amdgcn_cvt_pkrtz(S1.z, S1.w);                 \
    *(uint2*)(_b + 2048) = _c.u;                                      \
    _c.h[0] = __builtin_amdgcn_cvt_pkrtz(S2.x, S2.y);                 \
    _c.h[1] = __builtin_amdgcn_cvt_pkrtz(S2.z, S2.w);                 \
    *(uint2*)(_b + 4096) = _c.u;                                      \
    _c.h[0] = __builtin_amdgcn_cvt_pkrtz(S3.x, S3.y);                 \
    _c.h[1] = __builtin_amdgcn_cvt_pkrtz(S3.z, S3.w);                 \
    *(uint2*)(_b + 6144) = _c.u; }

  float m0[8], m1[8];
#pragma unroll
  for (int ct = 0; ct < 8; ++ct) { m0[ct] = -INFINITY; m1[ct] = -INFINITY; }

  auto compute = [&](const char* buf) {
#pragma unroll
    for (int rt = 0; rt < 2; ++rt) {
      const int row = rg * 32 + rt * 16 + cl;
      const int rx = cl & 7;                     // row&7 == cl&7
      const char* lp = buf + row * 128;
      f16x8 a0 = *(const f16x8*)(lp + ((o ^ rx) << 4));         // ksub 0
      f16x8 a1 = *(const f16x8*)(lp + (((4 + o) ^ rx) << 4));   // ksub 1
#pragma unroll
      for (int ct = 0; ct < 8; ++ct) {
        f32x4 acc = {0.f, 0.f, 0.f, 0.f};
        acc = __builtin_amdgcn_mfma_f32_16x16x32_f16(a0, bf[ct][0], acc, 0, 0, 0);
        acc = __builtin_amdgcn_mfma_f32_16x16x32_f16(a1, bf[ct][1], acc, 0, 0, 0);
        float h1 = fmaxf(acc[0], acc[1]), q1 = fminf(acc[0], acc[1]);
        float h2 = fmaxf(acc[2], acc[3]), q2 = fminf(acc[2], acc[3]);
        float M0 = fmaxf(h1, h2);
        float M1 = fmaxf(fminf(h1, h2), fmaxf(q1, q2));
        float old0 = m0[ct];
        m0[ct] = fmaxf(old0, M0);
        m1[ct] = fmaxf(m1[ct], fmaxf(fminf(old0, M0), M1));
      }
    }
  };

  char* buf0 = smem;
  char* buf1 = smem + CHBL;

  // ---- prologue: E=chunk0, O=chunk1; write chunk0 -> buf0; barrier ----
  float4 E0, E1, E2, E3, O0, O1, O2, O3;
  LOADG(E0, E1, E2, E3, 0)
  LOADG(O0, O1, O2, O3, 1)
  asm volatile("s_waitcnt vmcnt(4)" ::: "memory");   // E delivered
  CVTW(E0, E1, E2, E3, buf0)
  asm volatile("s_waitcnt lgkmcnt(0)" ::: "memory");
  __builtin_amdgcn_s_barrier();

  // ---- main loop: 15 x 2 chunks ----
#pragma unroll 1
  for (int q = 0; q < 15; ++q) {
    const int ch = 2 * q;
    LOADG(E0, E1, E2, E3, ch + 2)
    asm volatile("s_waitcnt vmcnt(4)" ::: "memory");   // O ready
    __builtin_amdgcn_sched_barrier(0);
    CVTW(O0, O1, O2, O3, buf1)
    compute(buf0);
    asm volatile("s_waitcnt lgkmcnt(0)" ::: "memory");
    __builtin_amdgcn_s_barrier();
    LOADG(O0, O1, O2, O3, ch + 3)
    asm volatile("s_waitcnt vmcnt(4)" ::: "memory");   // E ready
    __builtin_amdgcn_sched_barrier(0);
    CVTW(E0, E1, E2, E3, buf0)
    compute(buf1);
    asm volatile("s_waitcnt lgkmcnt(0)" ::: "memory");
    __builtin_amdgcn_s_barrier();
  }
  // ---- tail: chunks 30 (buf0), 31 (buf1) ----
  asm volatile("s_waitcnt vmcnt(0)" ::: "memory");
  __builtin_amdgcn_sched_barrier(0);
  CVTW(O0, O1, O2, O3, buf1)
  compute(buf0);
  asm volatile("s_waitcnt lgkmcnt(0)" ::: "memory");
  __builtin_amdgcn_s_barrier();
  compute(buf1);
#undef LOADG
#undef CVTW

  // ---- merge across the 4 k-octet groups within the wave; store ----
#pragma unroll
  for (int ct = 0; ct < 8; ++ct) {
#pragma unroll
    for (int off = 16; off <= 32; off <<= 1) {
      float p0 = __shfl_xor(m0[ct], off);
      float p1 = __shfl_xor(m1[ct], off);
      float n1 = fmaxf(fminf(m0[ct], p0), fmaxf(m1[ct], p1));
      m0[ct] = fmaxf(m0[ct], p0);
      m1[ct] = n1;
    }
    if (lane < 16) {
      const int col = cg * 128 + ct * 16 + lane;
      max0P[((size_t)a * 4 + half * 2 + rg) * BB + col] = m0[ct];
      max1P[((size_t)a * 4 + half * 2 + rg) * BB + col] = m1[ct];
    }
  }
}

// ---------------------------------------------------------------------------
// Kernel 2: per row b, merge the 4 partials per a, LSE over 511 logits,
// loss_b = LSE - diag.
// ---------------------------------------------------------------------------
__global__ __launch_bounds__(256) void lse_kernel(
    const float* __restrict__ max0P, const float* __restrict__ max1P,
    float* __restrict__ lossb)
{
  __shared__ float red[256];
  __shared__ float diag;
  const int b = blockIdx.x;
  const int t = threadIdx.x;     // t = a
  float M0 = -INFINITY, M1 = -INFINITY;
#pragma unroll
  for (int q = 0; q < 4; ++q) {
    float p0 = max0P[((size_t)t * 4 + q) * BB + b];
    float p1 = max1P[((size_t)t * 4 + q) * BB + b];
    float n1 = fmaxf(fminf(M0, p0), fmaxf(M1, p1));
    M0 = fmaxf(M0, p0);
    M1 = n1;
  }
  float x0 = M0;
  float x1 = (t == b) ? -INFINITY : M1;
  if (t == b) diag = x0;
  red[t] = fmaxf(x0, x1);
  __syncthreads();
  for (int s = 128; s > 0; s >>= 1) {
    if (t < s) red[t] = fmaxf(red[t], red[t + s]);
    __syncthreads();
  }
  float M = red[0];
  __syncthreads();
  float e = expf(x0 - M) + ((t == b) ? 0.0f : expf(x1 - M));
  red[t] = e;
  __syncthreads();
  for (int s = 128; s > 0; s >>= 1) {
    if (t < s) red[t] = red[t] + red[t + s];
    __syncthreads();
  }
  if (t == 0) lossb[b] = logf(red[0]) + M - diag;
}

__global__ __launch_bounds__(256) void mean_kernel(
    const float* __restrict__ lossb, float* __restrict__ out)
{
  __shared__ float red[256];
  const int t = threadIdx.x;
  red[t] = lossb[t];
  __syncthreads();
  for (int s = 128; s > 0; s >>= 1) {
    if (t < s) red[t] += red[t + s];
    __syncthreads();
  }
  if (t == 0) out[0] = red[0] * (1.0f / 256.0f);
}

extern "C" void kernel_launch(void* const* d_in, const int* in_sizes, int n_in,
                              void* d_out, int out_size, void* d_ws, size_t ws_size,
                              hipStream_t stream) {
  const float* F   = (const float*)d_in[0];   // fusion_fs [256,4096,64] fp32
  const float* lan = (const float*)d_in[1];   // lan_fs    [256,1,64]   fp32
  float* ws = (float*)d_ws;
  float* max0P = ws;                // [256*4*256] = 1 MB
  float* max1P = ws + 262144;       // [256*4*256] = 1 MB
  float* lossb = ws + 524288;       // [256]

  const int shmem = 2 * CHBL;       // 16 KB dynamic per block
  topk_sim_kernel<<<512, 256, shmem, stream>>>(F, lan, max0P, max1P);
  lse_kernel<<<256, 256, 0, stream>>>(max0P, max1P, lossb);
  mean_kernel<<<1, 256, 0, stream>>>(lossb, (float*)d_out);
}